// Round 14
// baseline (215.439 us; speedup 1.0000x reference)
//
#include <hip/hip_runtime.h>
#include <hip/hip_bf16.h>

// Problem constants (match reference)
#define NN 50000
#define EE 800000
#define EP (EE + NN)        // edges + self loops = 850000
#define DIN 128
#define HID 32
#define HEADS 8
#define C1 (HEADS * HID)    // 256
#define DOUT 16
#define NW1 3125            // gemm1/gemm2 waves: 50000/16
#define SH 9                // bucket shift: 512 nodes/bucket
#define NB 98               // ceil(50000/512)
#define CAP 16384           // per-bucket ebuf capacity (mean 8704, sigma~90)
#define EPT 8               // edges per thread in k_bucketA
#define BBLK (256 * EPT)    // 2048 edges per block
#define GB1 196             // gemm1 blocks in fat kernel (196*16 waves >= 3125)

typedef __attribute__((ext_vector_type(8))) short short8;   // 8 bf16 (4 VGPRs)
typedef __attribute__((ext_vector_type(4))) float float4v;  // MFMA C/D
typedef __attribute__((ext_vector_type(2))) float float2v;  // fp8 cvt result

__device__ inline unsigned short f2bf(float f) {
    __hip_bfloat16 b = __float2bfloat16(f);
    return *reinterpret_cast<unsigned short*>(&b);
}
__device__ inline float bflo(unsigned u) {
    union { unsigned int i; float f; } x;
    x.i = u << 16;
    return x.f;
}
__device__ inline float bfhi(unsigned u) {
    union { unsigned int i; float f; } x;
    x.i = u & 0xffff0000u;
    return x.f;
}
__device__ inline float bf2f(unsigned short u) {
    union { unsigned int i; float f; } x;
    x.i = ((unsigned int)u) << 16;
    return x.f;
}

// ---------------------------------------------------------------------------
// prep: gemm1 A-fragment image (17 tiles) + gemm2 B-fragment image + zero
// cntb (replaces the hipMemsetAsync launch). Runs FIRST (no dependencies).
// ---------------------------------------------------------------------------
__global__ void k_prepfw(const float* __restrict__ W1, const float* __restrict__ a1s,
                         const float* __restrict__ a1d, const float* __restrict__ W2,
                         unsigned short* __restrict__ w1frag,
                         unsigned short* __restrict__ w2frag,
                         int* __restrict__ cntb) {
    int i = blockIdx.x * 256 + threadIdx.x;
    if (blockIdx.x == 0 && threadIdx.x < NB) cntb[threadIdx.x] = 0;
    if (i < 17 * 2048) {
        int j = i & 7, lane = (i >> 3) & 63, s = (i >> 9) & 3, c = i >> 11;
        int q = lane >> 4, m = lane & 15;
        int k = s * 32 + q * 8 + j;
        float val;
        if (c < 16) {
            val = W1[k * C1 + c * 16 + m];
        } else {
            int h = m & 7;
            const float* av = (m < 8) ? a1s : a1d;
            float acc = 0.f;
            #pragma unroll
            for (int j2 = 0; j2 < 32; j2++)
                acc += W1[k * C1 + h * 32 + j2] * av[h * 32 + j2];
            val = acc;
        }
        w1frag[i] = f2bf(val);
    } else if (i < 17 * 2048 + 8 * 512) {
        int j2 = i - 17 * 2048;
        int jj = j2 & 7, lane = (j2 >> 3) & 63, s = j2 >> 9;
        int q = lane >> 4, m = lane & 15;
        w2frag[j2] = f2bf(W2[(s * 32 + q * 8 + jj) * DOUT + m]);
    }
}

// ---------------------------------------------------------------------------
// CSR pass 1: bucket edges by dst>>9. Packed entry: (src<<9)|(dst&511)
// (17+9=26 bits) -- halves ebuf write/read traffic. Per-wave histograms.
// ---------------------------------------------------------------------------
__global__ __launch_bounds__(256) void k_bucketA(const int* __restrict__ ei,
                                                 int* __restrict__ cntb,
                                                 unsigned* __restrict__ ebuf) {
    __shared__ int hist[4][NB];
    __shared__ int base[4][NB];
    int t = threadIdx.x;
    int wave = t >> 6;
    for (int i = t; i < 4 * NB; i += 256) ((int*)hist)[i] = 0;
    __syncthreads();
    int e0 = blockIdx.x * BBLK;
    int s[EPT], d[EPT], r[EPT];
    #pragma unroll
    for (int j = 0; j < EPT; j++) {
        int e = e0 + j * 256 + t;
        int ss = 0, dd = -1;
        if (e < EE) { ss = ei[e]; dd = ei[EE + e]; }
        else if (e < EP) { ss = e - EE; dd = ss; }   // self loop
        s[j] = ss; d[j] = dd;
        if (dd >= 0) r[j] = atomicAdd(&hist[wave][dd >> SH], 1);
    }
    __syncthreads();
    if (t < NB) {
        int h0 = hist[0][t], h1 = hist[1][t], h2 = hist[2][t], h3 = hist[3][t];
        int tot = h0 + h1 + h2 + h3;
        int bb = tot ? atomicAdd(&cntb[t], tot) : 0;
        base[0][t] = bb;
        base[1][t] = bb + h0;
        base[2][t] = bb + h0 + h1;
        base[3][t] = bb + h0 + h1 + h2;
    }
    __syncthreads();
    #pragma unroll
    for (int j = 0; j < EPT; j++) {
        if (d[j] >= 0) {
            int b = d[j] >> SH;
            ebuf[b * CAP + base[wave][b] + r[j]] =
                ((unsigned)s[j] << SH) | (unsigned)(d[j] & 511);
        }
    }
}

// ---------------------------------------------------------------------------
// FAT kernel: blocks 0..NB-1 run CSR pass 2 (one block per bucket);
// blocks NB.. run gemm1 (16 waves per 1024-thread block). The two halves
// are independent (csr needs bucketA; gemm1 needs prepfw) and co-schedule
// across CUs, removing one launch boundary and overlapping their time.
// ---------------------------------------------------------------------------
__global__ __launch_bounds__(1024) void k_csrgemm1(const int* __restrict__ cntb,
                                                   const unsigned* __restrict__ ebuf,
                                                   int* __restrict__ row_ptr,
                                                   int* __restrict__ esrc,
                                                   const float* __restrict__ x,
                                                   const unsigned short* __restrict__ w1frag,
                                                   unsigned char* __restrict__ h1f8,
                                                   float* __restrict__ al1sd,
                                                   unsigned short* __restrict__ al1s8) {
    __shared__ int sdeg[512];
    __shared__ int wtot[8];
    __shared__ int bpart[2];
    if (blockIdx.x < NB) {
        // ---------------- CSR pass 2 ----------------
        int b = blockIdx.x;
        int t = threadIdx.x;
        int lane = t & 63, wave = t >> 6;
        int nodes0 = b << SH;
        if (t < 512) sdeg[t] = 0;
        if (t < 128) {
            int v = (t < b) ? cntb[t] : 0;
            #pragma unroll
            for (int off = 1; off < 64; off <<= 1) v += __shfl_xor(v, off, 64);
            if (lane == 0) bpart[wave] = v;
        }
        __syncthreads();
        int baseS = bpart[0] + bpart[1];
        int cnt = cntb[b];
        const unsigned* eb = ebuf + b * CAP;
        for (int i = t; i < cnt; i += 1024)
            atomicAdd(&sdeg[eb[i] & 511], 1);
        __syncthreads();
        int v = (t < 512) ? sdeg[t] : 0;
        int inc = v;
        #pragma unroll
        for (int off = 1; off < 64; off <<= 1) {
            int u = __shfl_up(inc, off, 64);
            if (lane >= off) inc += u;
        }
        if (t < 512 && lane == 63) wtot[wave] = inc;
        __syncthreads();
        if (wave == 0 && lane < 8) {
            int w = wtot[lane];
            int iw = w;
            #pragma unroll
            for (int off = 1; off < 8; off <<= 1) {
                int u = __shfl_up(iw, off, 64);
                if (lane >= off) iw += u;
            }
            wtot[lane] = iw - w;   // exclusive
        }
        __syncthreads();
        int excl = inc - v + ((t < 512) ? wtot[wave] : 0);
        __syncthreads();
        if (t < 512) {
            sdeg[t] = excl;
            int node = nodes0 + t;
            if (node < NN) row_ptr[node] = baseS + excl;
        }
        __syncthreads();
        for (int i = t; i < cnt; i += 1024) {
            unsigned e = eb[i];
            int pos = atomicAdd(&sdeg[e & 511], 1);
            esrc[baseS + pos] = (int)(e >> SH);
        }
        if (b == 0 && t == 0) row_ptr[NN] = EP;
    } else {
        // ---------------- GEMM1 (wave-indexed) ----------------
        int wid = (blockIdx.x - NB) * 16 + (threadIdx.x >> 6);
        int lane = threadIdx.x & 63;
        if (wid >= NW1) return;
        int nb = wid * 16;
        int m = lane & 15, quad = lane >> 4;
        const float* xrow = x + (nb + m) * DIN;

        short8 bfr[4];
        #pragma unroll
        for (int s = 0; s < 4; s++) {
            float4 f0 = *(const float4*)(xrow + s * 32 + quad * 8);
            float4 f1 = *(const float4*)(xrow + s * 32 + quad * 8 + 4);
            unsigned short* bp = (unsigned short*)&bfr[s];
            bp[0] = f2bf(f0.x); bp[1] = f2bf(f0.y); bp[2] = f2bf(f0.z); bp[3] = f2bf(f0.w);
            bp[4] = f2bf(f1.x); bp[5] = f2bf(f1.y); bp[6] = f2bf(f1.z); bp[7] = f2bf(f1.w);
        }

        float4v acc[17];
        #pragma unroll
        for (int c = 0; c < 17; c++) acc[c] = (float4v){0.f, 0.f, 0.f, 0.f};

        #pragma unroll
        for (int s = 0; s < 4; s++) {
            const unsigned short* fp = w1frag + (s * 64 + lane) * 8;
            #pragma unroll
            for (int c = 0; c < 17; c++) {
                short8 afrag = *(const short8*)(fp + c * 2048);
                acc[c] = __builtin_amdgcn_mfma_f32_16x16x32_bf16(afrag, bfr[s], acc[c], 0, 0, 0);
            }
        }

        int node = nb + m;
        #pragma unroll
        for (int c = 0; c < 16; c++) {
            unsigned pk = 0;
            pk = __builtin_amdgcn_cvt_pk_fp8_f32(acc[c][0], acc[c][1], pk, false);
            pk = __builtin_amdgcn_cvt_pk_fp8_f32(acc[c][2], acc[c][3], pk, true);
            *(unsigned*)(h1f8 + node * C1 + c * 16 + quad * 4) = pk;
        }
        *(float4*)(al1sd + node * 16 + quad * 4) =
            make_float4(acc[16][0], acc[16][1], acc[16][2], acc[16][3]);
        if (quad < 2) {   // src logits (rows 0-7) packed bf16
            uint2 pk;
            pk.x = (unsigned)f2bf(acc[16][0]) | ((unsigned)f2bf(acc[16][1]) << 16);
            pk.y = (unsigned)f2bf(acc[16][2]) | ((unsigned)f2bf(acc[16][3]) << 16);
            *(uint2*)(al1s8 + node * 8 + quad * 4) = pk;
        }
    }
}

// ---------------------------------------------------------------------------
// agg1 (single launch): one wave per dst node, two-phase, fp8 gather.
// ---------------------------------------------------------------------------
__global__ __launch_bounds__(256) void k_agg1(const int* __restrict__ row_ptr,
                                              const int* __restrict__ esrc,
                                              const unsigned char* __restrict__ h1f8,
                                              const unsigned short* __restrict__ al1s8,
                                              const float* __restrict__ al1sd,
                                              const float* __restrict__ b1,
                                              unsigned short* __restrict__ helu_b) {
    __shared__ float wbuf[4][64 * 8];
    __shared__ int   sbuf[4][64];
    int wslot = threadIdx.x >> 6;
    int L = threadIdx.x & 63;
    int d = (blockIdx.x * 256 + threadIdx.x) >> 6;
    int h = L >> 3;
    int start = row_ptr[d], end = row_ptr[d + 1];
    float4 ald0 = *(const float4*)(al1sd + d * 16 + 8);
    float4 ald1 = *(const float4*)(al1sd + d * 16 + 12);
    float* wrow = wbuf[wslot];
    int* srow = sbuf[wslot];
    float denom = 0.f;
    float4 acc = make_float4(0.f, 0.f, 0.f, 0.f);
    const int Lofs = L * 4;

    for (int base = start; base < end; base += 64) {
        int cnt = min(64, end - base);
        int s = d;
        float wv0 = 0.f, wv1 = 0.f, wv2 = 0.f, wv3 = 0.f;
        float wv4 = 0.f, wv5 = 0.f, wv6 = 0.f, wv7 = 0.f;
        if (L < cnt) {
            s = esrc[base + L];
            uint4 as = *(const uint4*)(al1s8 + s * 8);
            float e;
            e = bflo(as.x) + ald0.x; e = e > 0.f ? e : 0.2f * e; wv0 = __expf(e);
            e = bfhi(as.x) + ald0.y; e = e > 0.f ? e : 0.2f * e; wv1 = __expf(e);
            e = bflo(as.y) + ald0.z; e = e > 0.f ? e : 0.2f * e; wv2 = __expf(e);
            e = bfhi(as.y) + ald0.w; e = e > 0.f ? e : 0.2f * e; wv3 = __expf(e);
            e = bflo(as.z) + ald1.x; e = e > 0.f ? e : 0.2f * e; wv4 = __expf(e);
            e = bfhi(as.z) + ald1.y; e = e > 0.f ? e : 0.2f * e; wv5 = __expf(e);
            e = bflo(as.w) + ald1.z; e = e > 0.f ? e : 0.2f * e; wv6 = __expf(e);
            e = bfhi(as.w) + ald1.w; e = e > 0.f ? e : 0.2f * e; wv7 = __expf(e);
        }
        srow[L] = s;
        *(float4*)&wrow[L * 8]     = make_float4(wv0, wv1, wv2, wv3);
        *(float4*)&wrow[L * 8 + 4] = make_float4(wv4, wv5, wv6, wv7);
        int cnt4 = (cnt + 3) & ~3;
        for (int i = 0; i < cnt4; i += 4) {
            int s0 = srow[i], s1 = srow[i + 1], s2 = srow[i + 2], s3 = srow[i + 3];
            float x0 = wrow[i * 8 + h];
            float x1 = wrow[i * 8 + 8 + h];
            float x2 = wrow[i * 8 + 16 + h];
            float x3 = wrow[i * 8 + 24 + h];
            unsigned v0 = *(const unsigned*)(h1f8 + s0 * C1 + Lofs);
            unsigned v1 = *(const unsigned*)(h1f8 + s1 * C1 + Lofs);
            unsigned v2 = *(const unsigned*)(h1f8 + s2 * C1 + Lofs);
            unsigned v3 = *(const unsigned*)(h1f8 + s3 * C1 + Lofs);
            denom += (x0 + x1) + (x2 + x3);
            float2v a, b;
            a = __builtin_amdgcn_cvt_pk_f32_fp8(v0, false);
            b = __builtin_amdgcn_cvt_pk_f32_fp8(v0, true);
            acc.x += x0 * a.x; acc.y += x0 * a.y; acc.z += x0 * b.x; acc.w += x0 * b.y;
            a = __builtin_amdgcn_cvt_pk_f32_fp8(v1, false);
            b = __builtin_amdgcn_cvt_pk_f32_fp8(v1, true);
            acc.x += x1 * a.x; acc.y += x1 * a.y; acc.z += x1 * b.x; acc.w += x1 * b.y;
            a = __builtin_amdgcn_cvt_pk_f32_fp8(v2, false);
            b = __builtin_amdgcn_cvt_pk_f32_fp8(v2, true);
            acc.x += x2 * a.x; acc.y += x2 * a.y; acc.z += x2 * b.x; acc.w += x2 * b.y;
            a = __builtin_amdgcn_cvt_pk_f32_fp8(v3, false);
            b = __builtin_amdgcn_cvt_pk_f32_fp8(v3, true);
            acc.x += x3 * a.x; acc.y += x3 * a.y; acc.z += x3 * b.x; acc.w += x3 * b.y;
        }
    }
    float inv = 1.0f / (denom + 1e-16f);
    float4 bv = *(const float4*)(b1 + Lofs);
    float o0 = acc.x * inv + bv.x;
    float o1 = acc.y * inv + bv.y;
    float o2 = acc.z * inv + bv.z;
    float o3 = acc.w * inv + bv.w;
    o0 = o0 > 0.f ? o0 : __expf(o0) - 1.0f;
    o1 = o1 > 0.f ? o1 : __expf(o1) - 1.0f;
    o2 = o2 > 0.f ? o2 : __expf(o2) - 1.0f;
    o3 = o3 > 0.f ? o3 : __expf(o3) - 1.0f;
    uint2 pk;
    pk.x = (unsigned)f2bf(o0) | ((unsigned)f2bf(o1) << 16);
    pk.y = (unsigned)f2bf(o2) | ((unsigned)f2bf(o3) << 16);
    *(uint2*)(helu_b + d * C1 + Lofs) = pk;
}

// ---------------------------------------------------------------------------
// GEMM2 via MFMA + fused al2 epilogue (w2frag fragment-image B loads).
// ---------------------------------------------------------------------------
__global__ __launch_bounds__(256) void k_gemm2(const unsigned short* __restrict__ helu_b,
                                               const unsigned short* __restrict__ w2frag,
                                               const float* __restrict__ a2s,
                                               const float* __restrict__ a2d,
                                               unsigned short* __restrict__ h2b,
                                               float* __restrict__ al2s,
                                               float* __restrict__ al2d) {
    int wid = (blockIdx.x * 256 + threadIdx.x) >> 6;
    int lane = threadIdx.x & 63;
    int nb = wid * 16;
    if (nb >= NN) return;
    int m = lane & 15, quad = lane >> 4;

    const unsigned short* wp2 = w2frag + lane * 8;
    float4v acc = {0.f, 0.f, 0.f, 0.f};
    const unsigned short* arow = helu_b + (nb + m) * C1 + quad * 8;
    #pragma unroll
    for (int s = 0; s < 8; s++) {
        short8 afrag = *(const short8*)(arow + s * 32);
        short8 bfrag = *(const short8*)(wp2 + s * 512);
        acc = __builtin_amdgcn_mfma_f32_16x16x32_bf16(afrag, bfrag, acc, 0, 0, 0);
    }

    float as_c = a2s[m], ad_c = a2d[m];
    #pragma unroll
    for (int r = 0; r < 4; r++) {
        int node = nb + quad * 4 + r;
        float val = acc[r];
        h2b[node * DOUT + m] = f2bf(val);
        float ps = val * as_c;
        float pd = val * ad_c;
        ps += __shfl_xor(ps, 1, 64); ps += __shfl_xor(ps, 2, 64);
        ps += __shfl_xor(ps, 4, 64); ps += __shfl_xor(ps, 8, 64);
        pd += __shfl_xor(pd, 1, 64); pd += __shfl_xor(pd, 2, 64);
        pd += __shfl_xor(pd, 4, 64); pd += __shfl_xor(pd, 8, 64);
        if (m == 0) {
            al2s[node] = ps;
            al2d[node] = pd;
        }
    }
}

// ---------------------------------------------------------------------------
// agg2 + bias + log_softmax (unchanged two-phase).
// ---------------------------------------------------------------------------
__global__ __launch_bounds__(256) void k_agg2(const int* __restrict__ row_ptr,
                                              const int* __restrict__ esrc,
                                              const unsigned short* __restrict__ h2b,
                                              const float* __restrict__ al2s,
                                              const float* __restrict__ al2d,
                                              const float* __restrict__ b2,
                                              float* __restrict__ out) {
    __shared__ float wbuf2[4][64];
    __shared__ int   sbuf2[4][64];
    int wslot = threadIdx.x >> 6;
    int L = threadIdx.x & 63;
    int n = (blockIdx.x * 256 + threadIdx.x) >> 6;
    if (n >= NN) return;
    int c = L & 15, g = L >> 4;
    int start = row_ptr[n], end = row_ptr[n + 1];
    float ald = al2d[n];
    float* wrow = wbuf2[wslot];
    int* srow = sbuf2[wslot];
    float acc = 0.f, denom = 0.f;

    for (int base = start; base < end; base += 64) {
        int cnt = min(64, end - base);
        int s = n; float w = 0.f;
        if (L < cnt) {
            s = esrc[base + L];
            float e = al2s[s] + ald;
            e = e > 0.f ? e : 0.2f * e;
            w = __expf(e);
        }
        srow[L] = s;
        wrow[L] = w;
        int cnt4 = (cnt + 3) & ~3;
        for (int i = 0; i < cnt4; i += 4) {
            int idx = i + g;
            int ss = srow[idx];
            float ww = wrow[idx];
            float v = bf2f(h2b[ss * DOUT + c]);
            acc += ww * v;
            denom += ww;
        }
    }
    acc += __shfl_xor(acc, 16, 64);   acc += __shfl_xor(acc, 32, 64);
    denom += __shfl_xor(denom, 16, 64); denom += __shfl_xor(denom, 32, 64);
    float val = acc / (denom + 1e-16f) + b2[c];
    float m = val;
    #pragma unroll
    for (int mm = 1; mm < 16; mm <<= 1) m = fmaxf(m, __shfl_xor(m, mm, 64));
    float ex = __expf(val - m);
    float se = ex;
    #pragma unroll
    for (int mm = 1; mm < 16; mm <<= 1) se += __shfl_xor(se, mm, 64);
    if (L < 16) out[n * DOUT + c] = val - m - __logf(se);
}

// ---------------------------------------------------------------------------
extern "C" void kernel_launch(void* const* d_in, const int* in_sizes, int n_in,
                              void* d_out, int out_size, void* d_ws, size_t ws_size,
                              hipStream_t stream) {
    const float* x   = (const float*)d_in[0];
    const int*   ei  = (const int*)d_in[1];
    const float* W1  = (const float*)d_in[2];
    const float* a1s = (const float*)d_in[3];
    const float* a1d = (const float*)d_in[4];
    const float* b1  = (const float*)d_in[5];
    const float* W2  = (const float*)d_in[6];
    const float* a2s = (const float*)d_in[7];
    const float* a2d = (const float*)d_in[8];
    const float* b2  = (const float*)d_in[9];
    float* outp = (float*)d_out;

    // workspace layout
    unsigned char* h1f8    = (unsigned char*)d_ws;       // N*256 fp8 e4m3 (12.8 MB)
    unsigned short* helu_b = (unsigned short*)(h1f8 + NN * C1);  // N*256 bf16
    unsigned short* h2b    = helu_b + NN * C1;           // N*16 bf16
    unsigned short* w2frag = h2b + NN * DOUT;            // 4096 bf16 (frag order)
    unsigned short* w1frag = w2frag + 8 * 512;           // 34816 bf16
    unsigned short* al1s8  = w1frag + 17 * 2048;         // N*8 bf16 (src logits)
    float* al1sd = (float*)(al1s8 + NN * 8);             // N*16 fp32
    float* al2sb = al1sd + NN * 16;                      // N
    float* al2db = al2sb + NN;                           // N
    int* row_ptr = (int*)(al2db + NN);                   // N+1
    int* esrc    = row_ptr + NN + 1;                     // EP
    int* cntb    = esrc + EP;                            // NB
    // ebuf (packed ints, 6.4 MB) aliases helu_b (25.6 MB); consumed by
    // k_csrgemm1 before agg1 writes helu_b -- stream ordering guarantees it.
    unsigned* ebuf = (unsigned*)helu_b;                  // NB * CAP uint

    // chain: prep -> bucketA -> [csr || gemm1] -> agg1 -> gemm2 -> agg2
    k_prepfw<<<(17 * 2048 + 8 * 512 + 255) / 256, 256, 0, stream>>>(W1, a1s, a1d, W2, w1frag, w2frag, cntb);
    k_bucketA<<<(EP + BBLK - 1) / BBLK, 256, 0, stream>>>(ei, cntb, ebuf);
    k_csrgemm1<<<NB + GB1, 1024, 0, stream>>>(cntb, ebuf, row_ptr, esrc,
                                              x, w1frag, h1f8, al1sd, al1s8);
    k_agg1<<<12500, 256, 0, stream>>>(row_ptr, esrc, h1f8, al1s8, al1sd, b1, helu_b);
    k_gemm2<<<(NW1 * 64 + 255) / 256, 256, 0, stream>>>(helu_b, w2frag, a2s, a2d, h2b, al2sb, al2db);
    k_agg2<<<(NN * 64 + 255) / 256, 256, 0, stream>>>(row_ptr, esrc, h2b, al2sb, al2db, b2, outp);
}

// Round 15
// 205.259 us; speedup vs baseline: 1.0496x; 1.0496x over previous
//
#include <hip/hip_runtime.h>
#include <hip/hip_bf16.h>

// Problem constants (match reference)
#define NN 50000
#define EE 800000
#define EP (EE + NN)        // edges + self loops = 850000
#define DIN 128
#define HID 32
#define HEADS 8
#define C1 (HEADS * HID)    // 256
#define DOUT 16
#define NW1 3125            // gemm1/gemm2 waves: 50000/16
#define SH 9                // bucket shift: 512 nodes/bucket
#define NB 98               // ceil(50000/512)
#define CAP 16384           // per-bucket ebuf capacity (mean 8704, sigma~90)
#define EPT 8               // edges per thread in k_bucketA
#define BBLK (256 * EPT)    // 2048 edges per block

typedef __attribute__((ext_vector_type(8))) short short8;   // 8 bf16 (4 VGPRs)
typedef __attribute__((ext_vector_type(4))) float float4v;  // MFMA C/D
typedef __attribute__((ext_vector_type(2))) float float2v;  // fp8 cvt result

__device__ inline unsigned short f2bf(float f) {
    __hip_bfloat16 b = __float2bfloat16(f);
    return *reinterpret_cast<unsigned short*>(&b);
}
__device__ inline float bflo(unsigned u) {
    union { unsigned int i; float f; } x;
    x.i = u << 16;
    return x.f;
}
__device__ inline float bfhi(unsigned u) {
    union { unsigned int i; float f; } x;
    x.i = u & 0xffff0000u;
    return x.f;
}
__device__ inline float bf2f(unsigned short u) {
    union { unsigned int i; float f; } x;
    x.i = ((unsigned int)u) << 16;
    return x.f;
}

// ---------------------------------------------------------------------------
// prep: gemm1 A-fragment image (17 tiles) + gemm2 B-fragment image + zero
// cntb. Runs FIRST (no dependencies).
// ---------------------------------------------------------------------------
__global__ void k_prepfw(const float* __restrict__ W1, const float* __restrict__ a1s,
                         const float* __restrict__ a1d, const float* __restrict__ W2,
                         unsigned short* __restrict__ w1frag,
                         unsigned short* __restrict__ w2frag,
                         int* __restrict__ cntb) {
    int i = blockIdx.x * 256 + threadIdx.x;
    if (blockIdx.x == 0 && threadIdx.x < NB) cntb[threadIdx.x] = 0;
    if (i < 17 * 2048) {
        int j = i & 7, lane = (i >> 3) & 63, s = (i >> 9) & 3, c = i >> 11;
        int q = lane >> 4, m = lane & 15;
        int k = s * 32 + q * 8 + j;
        float val;
        if (c < 16) {
            val = W1[k * C1 + c * 16 + m];
        } else {
            int h = m & 7;
            const float* av = (m < 8) ? a1s : a1d;
            float acc = 0.f;
            #pragma unroll
            for (int j2 = 0; j2 < 32; j2++)
                acc += W1[k * C1 + h * 32 + j2] * av[h * 32 + j2];
            val = acc;
        }
        w1frag[i] = f2bf(val);
    } else if (i < 17 * 2048 + 8 * 512) {
        int j2 = i - 17 * 2048;
        int jj = j2 & 7, lane = (j2 >> 3) & 63, s = j2 >> 9;
        int q = lane >> 4, m = lane & 15;
        w2frag[j2] = f2bf(W2[(s * 32 + q * 8 + jj) * DOUT + m]);
    }
}

// ---------------------------------------------------------------------------
// CSR pass 1: bucket edges by dst>>9. Packed entry: (src<<9)|(dst&511).
// Per-wave LDS histograms (4 copies).
// ---------------------------------------------------------------------------
__global__ __launch_bounds__(256) void k_bucketA(const int* __restrict__ ei,
                                                 int* __restrict__ cntb,
                                                 unsigned* __restrict__ ebuf) {
    __shared__ int hist[4][NB];
    __shared__ int base[4][NB];
    int t = threadIdx.x;
    int wave = t >> 6;
    for (int i = t; i < 4 * NB; i += 256) ((int*)hist)[i] = 0;
    __syncthreads();
    int e0 = blockIdx.x * BBLK;
    int s[EPT], d[EPT], r[EPT];
    #pragma unroll
    for (int j = 0; j < EPT; j++) {
        int e = e0 + j * 256 + t;
        int ss = 0, dd = -1;
        if (e < EE) { ss = ei[e]; dd = ei[EE + e]; }
        else if (e < EP) { ss = e - EE; dd = ss; }   // self loop
        s[j] = ss; d[j] = dd;
        if (dd >= 0) r[j] = atomicAdd(&hist[wave][dd >> SH], 1);
    }
    __syncthreads();
    if (t < NB) {
        int h0 = hist[0][t], h1 = hist[1][t], h2 = hist[2][t], h3 = hist[3][t];
        int tot = h0 + h1 + h2 + h3;
        int bb = tot ? atomicAdd(&cntb[t], tot) : 0;
        base[0][t] = bb;
        base[1][t] = bb + h0;
        base[2][t] = bb + h0 + h1;
        base[3][t] = bb + h0 + h1 + h2;
    }
    __syncthreads();
    #pragma unroll
    for (int j = 0; j < EPT; j++) {
        if (d[j] >= 0) {
            int b = d[j] >> SH;
            ebuf[b * CAP + base[wave][b] + r[j]] =
                ((unsigned)s[j] << SH) | (unsigned)(d[j] & 511);
        }
    }
}

// ---------------------------------------------------------------------------
// CSR pass 2 (standalone again -- R14 fusion spilled gemm1's registers):
// one block per bucket; LDS count -> scan -> rank scatter.
// ---------------------------------------------------------------------------
__global__ __launch_bounds__(1024) void k_csr(const int* __restrict__ cntb,
                                              const unsigned* __restrict__ ebuf,
                                              int* __restrict__ row_ptr,
                                              int* __restrict__ esrc) {
    __shared__ int sdeg[512];
    __shared__ int wtot[8];
    __shared__ int bpart[2];
    int b = blockIdx.x;
    int t = threadIdx.x;
    int lane = t & 63, wave = t >> 6;
    int nodes0 = b << SH;
    if (t < 512) sdeg[t] = 0;
    if (t < 128) {
        int v = (t < b) ? cntb[t] : 0;
        #pragma unroll
        for (int off = 1; off < 64; off <<= 1) v += __shfl_xor(v, off, 64);
        if (lane == 0) bpart[wave] = v;
    }
    __syncthreads();
    int baseS = bpart[0] + bpart[1];
    int cnt = cntb[b];
    const unsigned* eb = ebuf + b * CAP;
    for (int i = t; i < cnt; i += 1024)
        atomicAdd(&sdeg[eb[i] & 511], 1);
    __syncthreads();
    int v = (t < 512) ? sdeg[t] : 0;
    int inc = v;
    #pragma unroll
    for (int off = 1; off < 64; off <<= 1) {
        int u = __shfl_up(inc, off, 64);
        if (lane >= off) inc += u;
    }
    if (t < 512 && lane == 63) wtot[wave] = inc;
    __syncthreads();
    if (wave == 0 && lane < 8) {
        int w = wtot[lane];
        int iw = w;
        #pragma unroll
        for (int off = 1; off < 8; off <<= 1) {
            int u = __shfl_up(iw, off, 64);
            if (lane >= off) iw += u;
        }
        wtot[lane] = iw - w;   // exclusive
    }
    __syncthreads();
    int excl = inc - v + ((t < 512) ? wtot[wave] : 0);
    __syncthreads();
    if (t < 512) {
        sdeg[t] = excl;
        int node = nodes0 + t;
        if (node < NN) row_ptr[node] = baseS + excl;
    }
    __syncthreads();
    for (int i = t; i < cnt; i += 1024) {
        unsigned e = eb[i];
        int pos = atomicAdd(&sdeg[e & 511], 1);
        esrc[baseS + pos] = (int)(e >> SH);
    }
    if (b == 0 && t == 0) row_ptr[NN] = EP;
}

// ---------------------------------------------------------------------------
// GEMM1 via MFMA (operand-swapped, standalone 256-thread blocks -- full
// register budget, no spill). fp8 h1 table + al1sd fp32 + al1s8 bf16.
// ---------------------------------------------------------------------------
__global__ __launch_bounds__(256) void k_gemm1(const float* __restrict__ x,
                                               const unsigned short* __restrict__ w1frag,
                                               unsigned char* __restrict__ h1f8,
                                               float* __restrict__ al1sd,
                                               unsigned short* __restrict__ al1s8) {
    int wid = (blockIdx.x * 256 + threadIdx.x) >> 6;
    int lane = threadIdx.x & 63;
    if (wid >= NW1) return;
    int nb = wid * 16;
    int m = lane & 15, quad = lane >> 4;
    const float* xrow = x + (nb + m) * DIN;

    float4 xf[8];
    #pragma unroll
    for (int s = 0; s < 4; s++) {
        xf[2 * s]     = *(const float4*)(xrow + s * 32 + quad * 8);
        xf[2 * s + 1] = *(const float4*)(xrow + s * 32 + quad * 8 + 4);
    }
    short8 bfr[4];
    #pragma unroll
    for (int s = 0; s < 4; s++) {
        unsigned short* bp = (unsigned short*)&bfr[s];
        float4 f0 = xf[2 * s], f1 = xf[2 * s + 1];
        bp[0] = f2bf(f0.x); bp[1] = f2bf(f0.y); bp[2] = f2bf(f0.z); bp[3] = f2bf(f0.w);
        bp[4] = f2bf(f1.x); bp[5] = f2bf(f1.y); bp[6] = f2bf(f1.z); bp[7] = f2bf(f1.w);
    }

    float4v acc[17];
    #pragma unroll
    for (int c = 0; c < 17; c++) acc[c] = (float4v){0.f, 0.f, 0.f, 0.f};

    #pragma unroll
    for (int s = 0; s < 4; s++) {
        const unsigned short* fp = w1frag + (s * 64 + lane) * 8;
        #pragma unroll
        for (int c = 0; c < 17; c++) {
            short8 afrag = *(const short8*)(fp + c * 2048);
            acc[c] = __builtin_amdgcn_mfma_f32_16x16x32_bf16(afrag, bfr[s], acc[c], 0, 0, 0);
        }
    }

    int node = nb + m;
    #pragma unroll
    for (int c = 0; c < 16; c++) {
        unsigned pk = 0;
        pk = __builtin_amdgcn_cvt_pk_fp8_f32(acc[c][0], acc[c][1], pk, false);
        pk = __builtin_amdgcn_cvt_pk_fp8_f32(acc[c][2], acc[c][3], pk, true);
        *(unsigned*)(h1f8 + node * C1 + c * 16 + quad * 4) = pk;
    }
    *(float4*)(al1sd + node * 16 + quad * 4) =
        make_float4(acc[16][0], acc[16][1], acc[16][2], acc[16][3]);
    if (quad < 2) {   // src logits (rows 0-7) packed bf16
        uint2 pk;
        pk.x = (unsigned)f2bf(acc[16][0]) | ((unsigned)f2bf(acc[16][1]) << 16);
        pk.y = (unsigned)f2bf(acc[16][2]) | ((unsigned)f2bf(acc[16][3]) << 16);
        *(uint2*)(al1s8 + node * 8 + quad * 4) = pk;
    }
}

// ---------------------------------------------------------------------------
// agg1 (single launch): one wave per dst node, two-phase, fp8 gather.
// ---------------------------------------------------------------------------
__global__ __launch_bounds__(256) void k_agg1(const int* __restrict__ row_ptr,
                                              const int* __restrict__ esrc,
                                              const unsigned char* __restrict__ h1f8,
                                              const unsigned short* __restrict__ al1s8,
                                              const float* __restrict__ al1sd,
                                              const float* __restrict__ b1,
                                              unsigned short* __restrict__ helu_b) {
    __shared__ float wbuf[4][64 * 8];
    __shared__ int   sbuf[4][64];
    int wslot = threadIdx.x >> 6;
    int L = threadIdx.x & 63;
    int d = (blockIdx.x * 256 + threadIdx.x) >> 6;
    int h = L >> 3;
    int start = row_ptr[d], end = row_ptr[d + 1];
    float4 ald0 = *(const float4*)(al1sd + d * 16 + 8);
    float4 ald1 = *(const float4*)(al1sd + d * 16 + 12);
    float* wrow = wbuf[wslot];
    int* srow = sbuf[wslot];
    float denom = 0.f;
    float4 acc = make_float4(0.f, 0.f, 0.f, 0.f);
    const int Lofs = L * 4;

    for (int base = start; base < end; base += 64) {
        int cnt = min(64, end - base);
        int s = d;
        float wv0 = 0.f, wv1 = 0.f, wv2 = 0.f, wv3 = 0.f;
        float wv4 = 0.f, wv5 = 0.f, wv6 = 0.f, wv7 = 0.f;
        if (L < cnt) {
            s = esrc[base + L];
            uint4 as = *(const uint4*)(al1s8 + s * 8);
            float e;
            e = bflo(as.x) + ald0.x; e = e > 0.f ? e : 0.2f * e; wv0 = __expf(e);
            e = bfhi(as.x) + ald0.y; e = e > 0.f ? e : 0.2f * e; wv1 = __expf(e);
            e = bflo(as.y) + ald0.z; e = e > 0.f ? e : 0.2f * e; wv2 = __expf(e);
            e = bfhi(as.y) + ald0.w; e = e > 0.f ? e : 0.2f * e; wv3 = __expf(e);
            e = bflo(as.z) + ald1.x; e = e > 0.f ? e : 0.2f * e; wv4 = __expf(e);
            e = bfhi(as.z) + ald1.y; e = e > 0.f ? e : 0.2f * e; wv5 = __expf(e);
            e = bflo(as.w) + ald1.z; e = e > 0.f ? e : 0.2f * e; wv6 = __expf(e);
            e = bfhi(as.w) + ald1.w; e = e > 0.f ? e : 0.2f * e; wv7 = __expf(e);
        }
        srow[L] = s;
        *(float4*)&wrow[L * 8]     = make_float4(wv0, wv1, wv2, wv3);
        *(float4*)&wrow[L * 8 + 4] = make_float4(wv4, wv5, wv6, wv7);
        int cnt4 = (cnt + 3) & ~3;
        for (int i = 0; i < cnt4; i += 4) {
            int s0 = srow[i], s1 = srow[i + 1], s2 = srow[i + 2], s3 = srow[i + 3];
            float x0 = wrow[i * 8 + h];
            float x1 = wrow[i * 8 + 8 + h];
            float x2 = wrow[i * 8 + 16 + h];
            float x3 = wrow[i * 8 + 24 + h];
            unsigned v0 = *(const unsigned*)(h1f8 + s0 * C1 + Lofs);
            unsigned v1 = *(const unsigned*)(h1f8 + s1 * C1 + Lofs);
            unsigned v2 = *(const unsigned*)(h1f8 + s2 * C1 + Lofs);
            unsigned v3 = *(const unsigned*)(h1f8 + s3 * C1 + Lofs);
            denom += (x0 + x1) + (x2 + x3);
            float2v a, b;
            a = __builtin_amdgcn_cvt_pk_f32_fp8(v0, false);
            b = __builtin_amdgcn_cvt_pk_f32_fp8(v0, true);
            acc.x += x0 * a.x; acc.y += x0 * a.y; acc.z += x0 * b.x; acc.w += x0 * b.y;
            a = __builtin_amdgcn_cvt_pk_f32_fp8(v1, false);
            b = __builtin_amdgcn_cvt_pk_f32_fp8(v1, true);
            acc.x += x1 * a.x; acc.y += x1 * a.y; acc.z += x1 * b.x; acc.w += x1 * b.y;
            a = __builtin_amdgcn_cvt_pk_f32_fp8(v2, false);
            b = __builtin_amdgcn_cvt_pk_f32_fp8(v2, true);
            acc.x += x2 * a.x; acc.y += x2 * a.y; acc.z += x2 * b.x; acc.w += x2 * b.y;
            a = __builtin_amdgcn_cvt_pk_f32_fp8(v3, false);
            b = __builtin_amdgcn_cvt_pk_f32_fp8(v3, true);
            acc.x += x3 * a.x; acc.y += x3 * a.y; acc.z += x3 * b.x; acc.w += x3 * b.y;
        }
    }
    float inv = 1.0f / (denom + 1e-16f);
    float4 bv = *(const float4*)(b1 + Lofs);
    float o0 = acc.x * inv + bv.x;
    float o1 = acc.y * inv + bv.y;
    float o2 = acc.z * inv + bv.z;
    float o3 = acc.w * inv + bv.w;
    o0 = o0 > 0.f ? o0 : __expf(o0) - 1.0f;
    o1 = o1 > 0.f ? o1 : __expf(o1) - 1.0f;
    o2 = o2 > 0.f ? o2 : __expf(o2) - 1.0f;
    o3 = o3 > 0.f ? o3 : __expf(o3) - 1.0f;
    uint2 pk;
    pk.x = (unsigned)f2bf(o0) | ((unsigned)f2bf(o1) << 16);
    pk.y = (unsigned)f2bf(o2) | ((unsigned)f2bf(o3) << 16);
    *(uint2*)(helu_b + d * C1 + Lofs) = pk;
}

// ---------------------------------------------------------------------------
// GEMM2 via MFMA + fused al2 epilogue (w2frag fragment-image B loads).
// ---------------------------------------------------------------------------
__global__ __launch_bounds__(256) void k_gemm2(const unsigned short* __restrict__ helu_b,
                                               const unsigned short* __restrict__ w2frag,
                                               const float* __restrict__ a2s,
                                               const float* __restrict__ a2d,
                                               unsigned short* __restrict__ h2b,
                                               float* __restrict__ al2s,
                                               float* __restrict__ al2d) {
    int wid = (blockIdx.x * 256 + threadIdx.x) >> 6;
    int lane = threadIdx.x & 63;
    int nb = wid * 16;
    if (nb >= NN) return;
    int m = lane & 15, quad = lane >> 4;

    const unsigned short* wp2 = w2frag + lane * 8;
    float4v acc = {0.f, 0.f, 0.f, 0.f};
    const unsigned short* arow = helu_b + (nb + m) * C1 + quad * 8;
    #pragma unroll
    for (int s = 0; s < 8; s++) {
        short8 afrag = *(const short8*)(arow + s * 32);
        short8 bfrag = *(const short8*)(wp2 + s * 512);
        acc = __builtin_amdgcn_mfma_f32_16x16x32_bf16(afrag, bfrag, acc, 0, 0, 0);
    }

    float as_c = a2s[m], ad_c = a2d[m];
    #pragma unroll
    for (int r = 0; r < 4; r++) {
        int node = nb + quad * 4 + r;
        float val = acc[r];
        h2b[node * DOUT + m] = f2bf(val);
        float ps = val * as_c;
        float pd = val * ad_c;
        ps += __shfl_xor(ps, 1, 64); ps += __shfl_xor(ps, 2, 64);
        ps += __shfl_xor(ps, 4, 64); ps += __shfl_xor(ps, 8, 64);
        pd += __shfl_xor(pd, 1, 64); pd += __shfl_xor(pd, 2, 64);
        pd += __shfl_xor(pd, 4, 64); pd += __shfl_xor(pd, 8, 64);
        if (m == 0) {
            al2s[node] = ps;
            al2d[node] = pd;
        }
    }
}

// ---------------------------------------------------------------------------
// agg2 + bias + log_softmax: one wave per node, two-phase. Phase 2 NOW
// 8 edge-slots x 8 uint lanes (2 packed bf16 channels each) -- 8 edges per
// wave-iteration instead of 4 with the same instruction count. Reduction
// over slot bits (xor 8/16/32); epilogue reduces channel-pair bits 1/2/4.
// ---------------------------------------------------------------------------
__global__ __launch_bounds__(256) void k_agg2(const int* __restrict__ row_ptr,
                                              const int* __restrict__ esrc,
                                              const unsigned short* __restrict__ h2b,
                                              const float* __restrict__ al2s,
                                              const float* __restrict__ al2d,
                                              const float* __restrict__ b2,
                                              float* __restrict__ out) {
    __shared__ float wbuf2[4][64];
    __shared__ int   sbuf2[4][64];
    int wslot = threadIdx.x >> 6;
    int L = threadIdx.x & 63;
    int n = (blockIdx.x * 256 + threadIdx.x) >> 6;
    if (n >= NN) return;
    int p = L & 7, g = L >> 3;          // channel-pair, edge-slot
    int start = row_ptr[n], end = row_ptr[n + 1];
    float ald = al2d[n];
    float* wrow = wbuf2[wslot];
    int* srow = sbuf2[wslot];
    float acc0 = 0.f, acc1 = 0.f, denom = 0.f;

    for (int base = start; base < end; base += 64) {
        int cnt = min(64, end - base);
        int s = n; float w = 0.f;
        if (L < cnt) {
            s = esrc[base + L];
            float e = al2s[s] + ald;
            e = e > 0.f ? e : 0.2f * e;
            w = __expf(e);
        }
        srow[L] = s;
        wrow[L] = w;
        int cnt8 = (cnt + 7) & ~7;
        for (int i = 0; i < cnt8; i += 8) {
            int idx = i + g;
            int ss = srow[idx];
            float ww = wrow[idx];
            unsigned v = *(const unsigned*)(h2b + ss * DOUT + p * 2);
            acc0 += ww * bflo(v);
            acc1 += ww * bfhi(v);
            denom += ww;
        }
    }
    // reduce over the 8 edge-slots (xor bits 3..5 keep p)
    acc0 += __shfl_xor(acc0, 8, 64);  acc0 += __shfl_xor(acc0, 16, 64);  acc0 += __shfl_xor(acc0, 32, 64);
    acc1 += __shfl_xor(acc1, 8, 64);  acc1 += __shfl_xor(acc1, 16, 64);  acc1 += __shfl_xor(acc1, 32, 64);
    denom += __shfl_xor(denom, 8, 64); denom += __shfl_xor(denom, 16, 64); denom += __shfl_xor(denom, 32, 64);
    float inv = 1.0f / (denom + 1e-16f);
    float2 bv = *(const float2*)(b2 + p * 2);
    float val0 = acc0 * inv + bv.x;
    float val1 = acc1 * inv + bv.y;
    // log_softmax over 16 channels = 8 pairs x 2
    float m = fmaxf(val0, val1);
    #pragma unroll
    for (int mm = 1; mm < 8; mm <<= 1) m = fmaxf(m, __shfl_xor(m, mm, 64));
    float se = __expf(val0 - m) + __expf(val1 - m);
    #pragma unroll
    for (int mm = 1; mm < 8; mm <<= 1) se += __shfl_xor(se, mm, 64);
    float lse = m + __logf(se);
    if (L < 8) {
        float2 o = make_float2(val0 - lse, val1 - lse);
        *(float2*)(out + n * DOUT + p * 2) = o;
    }
}

// ---------------------------------------------------------------------------
extern "C" void kernel_launch(void* const* d_in, const int* in_sizes, int n_in,
                              void* d_out, int out_size, void* d_ws, size_t ws_size,
                              hipStream_t stream) {
    const float* x   = (const float*)d_in[0];
    const int*   ei  = (const int*)d_in[1];
    const float* W1  = (const float*)d_in[2];
    const float* a1s = (const float*)d_in[3];
    const float* a1d = (const float*)d_in[4];
    const float* b1  = (const float*)d_in[5];
    const float* W2  = (const float*)d_in[6];
    const float* a2s = (const float*)d_in[7];
    const float* a2d = (const float*)d_in[8];
    const float* b2  = (const float*)d_in[9];
    float* outp = (float*)d_out;

    // workspace layout
    unsigned char* h1f8    = (unsigned char*)d_ws;       // N*256 fp8 e4m3 (12.8 MB)
    unsigned short* helu_b = (unsigned short*)(h1f8 + NN * C1);  // N*256 bf16
    unsigned short* h2b    = helu_b + NN * C1;           // N*16 bf16
    unsigned short* w2frag = h2b + NN * DOUT;            // 4096 bf16 (frag order)
    unsigned short* w1frag = w2frag + 8 * 512;           // 34816 bf16
    unsigned short* al1s8  = w1frag + 17 * 2048;         // N*8 bf16 (src logits)
    float* al1sd = (float*)(al1s8 + NN * 8);             // N*16 fp32
    float* al2sb = al1sd + NN * 16;                      // N
    float* al2db = al2sb + NN;                           // N
    int* row_ptr = (int*)(al2db + NN);                   // N+1
    int* esrc    = row_ptr + NN + 1;                     // EP
    int* cntb    = esrc + EP;                            // NB
    // ebuf (packed ints, 6.4 MB) aliases helu_b (25.6 MB); consumed by k_csr
    // before agg1 writes helu_b -- stream ordering guarantees it.
    unsigned* ebuf = (unsigned*)helu_b;                  // NB * CAP uint

    // chain: prep -> bucketA -> gemm1 -> csr -> agg1 -> gemm2 -> agg2
    k_prepfw<<<(17 * 2048 + 8 * 512 + 255) / 256, 256, 0, stream>>>(W1, a1s, a1d, W2, w1frag, w2frag, cntb);
    k_bucketA<<<(EP + BBLK - 1) / BBLK, 256, 0, stream>>>(ei, cntb, ebuf);
    k_gemm1<<<(NW1 * 64 + 255) / 256, 256, 0, stream>>>(x, w1frag, h1f8, al1sd, al1s8);
    k_csr<<<NB, 1024, 0, stream>>>(cntb, ebuf, row_ptr, esrc);
    k_agg1<<<12500, 256, 0, stream>>>(row_ptr, esrc, h1f8, al1s8, al1sd, b1, helu_b);
    k_gemm2<<<(NW1 * 64 + 255) / 256, 256, 0, stream>>>(helu_b, w2frag, a2s, a2d, h2b, al2sb, al2db);
    k_agg2<<<(NN * 64 + 255) / 256, 256, 0, stream>>>(row_ptr, esrc, h2b, al2sb, al2db, b2, outp);
}